// Round 6
// baseline (122.295 us; speedup 1.0000x reference)
//
#include <hip/hip_runtime.h>

// NormalizePixelPts: out[f][d] = in[f][d] * scale(d), scale in {1, 1/1280, 1/720}.
// Flat float4 view: n4 = 17,113,088 = 2089 (phase period, prime) x 8192 (reps).
// Decomposition: grid.x = 9 phase tiles (256 threads each; last tile ragged, 41
// active), grid.y = 256 rep-chunks of 32 reps. Total 2304 blocks = exactly
// 9 blocks/CU (balanced). Each thread owns ONE phase: scale quad computed once
// into REGISTERS; inner loop is pure load/mul/store, stride 2089 float4s.
// Regular (cached) loads/stores — NT hints measured -15% in round 4.

#define FEAT_DIM 4178
#define SPLIT    570
#define KBLK     285
#define HALF     2089        // float4-phase period (prime)
#define REPS_TOTAL 8192      // n4 / HALF
#define REPS_PER_BLOCK 32    // REPS_TOTAL / 256

typedef float f4 __attribute__((ext_vector_type(4)));

__device__ __forceinline__ float scale_for(int d) {
    const float inv_w = 1.0f / 1280.0f;
    const float inv_h = 1.0f / 720.0f;
    if (d >= FEAT_DIM) d -= FEAT_DIM;   // callers pass d < 2*FEAT_DIM
    if (d < SPLIT) {
        int r = d % KBLK;
        if (r == 0 || r == 81 || r >= 164) return 1.0f;
        if (r <= 80) return ((r - 1) & 1) ? inv_h : inv_w;
        return ((r - 82) & 1) ? inv_h : inv_w;  // 82..163 incl. RH-LH pair
    }
    return ((d - 570) & 1) ? inv_h : inv_w;
}

__global__ void __launch_bounds__(256)
normalize_pixel_pts_kernel(const f4* __restrict__ in, f4* __restrict__ out) {
    int p = blockIdx.x * 256 + threadIdx.x;   // phase in [0, 2089)
    if (p >= HALF) return;

    // Per-thread scale quad, computed ONCE (off the hot path).
    int d0 = 4 * p;                        // <= 8352 < 2*FEAT_DIM
    if (d0 >= FEAT_DIM) d0 -= FEAT_DIM;    // even, <= 4176
    f4 s;
    s.x = scale_for(d0);
    s.y = scale_for(d0 + 1);
    s.z = scale_for(d0 + 2);               // may wrap (handled in scale_for)
    s.w = scale_for(d0 + 3);

    int i = blockIdx.y * (REPS_PER_BLOCK * HALF) + p;   // max < 17,113,088
    #pragma unroll 4
    for (int r = 0; r < REPS_PER_BLOCK; ++r, i += HALF) {
        f4 v = in[i];
        v *= s;
        out[i] = v;
    }
}

extern "C" void kernel_launch(void* const* d_in, const int* in_sizes, int n_in,
                              void* d_out, int out_size, void* d_ws, size_t ws_size,
                              hipStream_t stream) {
    const f4* in = (const f4*)d_in[0];
    f4* out = (f4*)d_out;
    // out_size = 68,452,352 = 4 * 2089 * 8192 exactly.
    dim3 grid((HALF + 255) / 256,            // 9 phase tiles
              REPS_TOTAL / REPS_PER_BLOCK);  // 256 rep chunks -> 2304 blocks = 9/CU
    normalize_pixel_pts_kernel<<<grid, dim3(256, 1, 1), 0, stream>>>(in, out);
}